// Round 15
// baseline (390.665 us; speedup 1.0000x reference)
//
#include <hip/hip_runtime.h>
#include <hip/hip_bf16.h>
#include <hip/hip_fp16.h>
#include <stdint.h>

#define N_NODESC 25000
#define N_EDGESC 400000
#define N_GRAPHSC 64
#define F_INC 128
#define HIDC 512
#define PSTRIDE 1600000   // elements per 64-col panel: 25000*64
#define MTILES 196        // ceil(25000/128)

typedef __attribute__((ext_vector_type(8))) short short8;
typedef __attribute__((ext_vector_type(8))) _Float16 half8;
typedef __attribute__((ext_vector_type(4))) float f32x4;

__device__ __forceinline__ unsigned short f2h(float f) {
  return __half_as_ushort(__float2half_rn(f));
}

// ================= fused prep (1 launch):
//  blocks [0,1563): degree count via atomicAdd on UNIFORM-init deg (poison-agnostic;
//                   true degree recovered in scan via sentinel deg[25000])
//  blocks [1563,4688): x -> fp16 panel-major
//  blocks [4688,4848): weight transposes (LDS tiles)
//  blocks [4848,4976): zero gsum
__global__ __launch_bounds__(256)
void prep_kernel(const float* __restrict__ x, const int* __restrict__ ei,
                 const float* __restrict__ W1rel, const float* __restrict__ W1root,
                 const float* __restrict__ W2rel, const float* __restrict__ W2root,
                 unsigned short* __restrict__ xp, unsigned short* __restrict__ W1T,
                 unsigned short* __restrict__ W2T, int* __restrict__ deg,
                 float* __restrict__ gsum) {
  int blk = blockIdx.x, t = threadIdx.x;
  if (blk < 1563) {                              // degree histogram (no pre-zero needed)
    int e = blk * 256 + t;
    if (e < N_EDGESC) atomicAdd(&deg[ei[N_EDGESC + e]], 1);
  } else if (blk < 4688) {                       // 3125 blocks: 3.2M elems / 4
    int idx = ((blk - 1563) * 256 + t) * 4;
    int node = idx >> 7;
    int col = idx & 127;
    float4 v = *(const float4*)(x + idx);
    ushort4 o;
    o.x = f2h(v.x); o.y = f2h(v.y); o.z = f2h(v.z); o.w = f2h(v.w);
    *(ushort4*)(xp + (size_t)(col >> 6) * PSTRIDE + (size_t)node * 64 + (col & 63)) = o;
  } else if (blk < 4848) {                       // 160 blocks: weight transposes
    __shared__ float tile[64][65];
    int b2 = blk - 4688;
    const float* src;
    unsigned short* dst;
    int n0, k0, Kout;
    if (b2 < 128) {                              // W2: k-tiles 16, n-tiles 8
      int kt = b2 >> 3, nt = b2 & 7;
      k0 = kt * 64; n0 = nt * 64;
      src = (k0 < 512) ? (W2rel + (size_t)k0 * 512) : (W2root + (size_t)(k0 - 512) * 512);
      dst = W2T; Kout = 1024;
    } else {                                     // W1: k-tiles 4, n-tiles 8
      int b = b2 - 128;
      int kt = b >> 3, nt = b & 7;
      k0 = kt * 64; n0 = nt * 64;
      src = (k0 < 128) ? (W1rel + (size_t)k0 * 512) : (W1root + (size_t)(k0 - 128) * 512);
      dst = W1T; Kout = 256;
    }
    int c = t & 63;
    int r4 = t >> 6;
#pragma unroll
    for (int rr = 0; rr < 64; rr += 4) {
      int row = rr + r4;
      tile[c][row] = src[(size_t)row * 512 + n0 + c];
    }
    __syncthreads();
#pragma unroll
    for (int rr = 0; rr < 64; rr += 4) {
      int nrow = rr + r4;
      dst[(size_t)(n0 + nrow) * Kout + k0 + c] = f2h(tile[nrow][c]);
    }
  } else {                                       // 128 blocks: gsum 64x512
    int i = (blk - 4848) * 256 + t;
    if (i < N_GRAPHSC * HIDC) gsum[i] = 0.f;
  }
}

// single-block: subtract uniform base (sentinel deg[N_NODESC] untouched by prep),
// exclusive scan -> indptr/cursor, counting sort of node ids by degree -> sorted.
__global__ __launch_bounds__(1024)
void scan_kernel(const int* __restrict__ deg, int* __restrict__ indptr, int* __restrict__ cursor,
                 int* __restrict__ sorted) {
  __shared__ int sums[1024];
  __shared__ int bins[256];
  __shared__ int binptr[256];
  const int t = threadIdx.x;
  const int CH = (N_NODESC + 1023) / 1024;  // 25
  const int base = t * CH;
  const unsigned ub = (unsigned)deg[N_NODESC];   // uniform init value (poison or 0)
  if (t < 256) bins[t] = 0;
  __syncthreads();
  int dl[CH];
  int s = 0;
  for (int i = 0; i < CH; ++i) {
    int idx = base + i;
    int d = (idx < N_NODESC) ? (int)((unsigned)deg[idx] - ub) : -1;
    dl[i] = d;
    if (d >= 0) {
      s += d;
      atomicAdd(&bins[d > 255 ? 255 : d], 1);
    }
  }
  sums[t] = s;
  __syncthreads();
  for (int off = 1; off < 1024; off <<= 1) {
    int v = (t >= off) ? sums[t - off] : 0;
    __syncthreads();
    sums[t] += v;
    __syncthreads();
  }
  if (t == 0) {
    int run = 0;
    for (int b = 0; b < 256; ++b) { binptr[b] = run; run += bins[b]; }
  }
  __syncthreads();
  int run = (t > 0) ? sums[t - 1] : 0;
  for (int i = 0; i < CH; ++i) {
    int idx = base + i;
    if (idx < N_NODESC) {
      indptr[idx] = run;
      cursor[idx] = run;
      run += dl[i];
      int pos = atomicAdd(&binptr[dl[i] > 255 ? 255 : dl[i]], 1);
      sorted[pos] = idx;
    }
  }
  if (t == 0) indptr[N_NODESC] = sums[1023];
}

// packed edge meta: src (16b) | fp16 weight (16b)
__global__ void fill_kernel(const int* __restrict__ ei, const float* __restrict__ ea,
                            int* __restrict__ cursor, unsigned* __restrict__ emeta) {
  int e = blockIdx.x * blockDim.x + threadIdx.x;
  if (e >= N_EDGESC) return;
  int dst = ei[N_EDGESC + e];
  int pos = atomicAdd(&cursor[dst], 1);
  unsigned short hw = __half_as_ushort(__float2half_rn(ea[e]));
  emeta[pos] = (unsigned)ei[e] | ((unsigned)hw << 16);
}

// ================= panel-major CSR gather (L2-blocked, 8 nodes per wave, fp16) =====
__global__ __launch_bounds__(256)
void agg_gather_s(const unsigned short* __restrict__ feat, const int* __restrict__ indptr,
                  const unsigned* __restrict__ emeta, const int* __restrict__ sorted,
                  unsigned short* __restrict__ outp, int lgP) {
  int panel = blockIdx.x & ((1 << lgP) - 1);
  int nidx = (blockIdx.x >> lgP) * 32 + (threadIdx.x >> 3);   // 32 node-slots / block
  if (nidx >= N_NODESC) return;
  int c8 = threadIdx.x & 7;
  int node = sorted[nidx];
  int beg = indptr[node];
  int deg = indptr[node + 1] - beg;
  const unsigned* mp = emeta + beg;
  const char* fb = (const char*)(feat + (size_t)panel * PSTRIDE);
  unsigned coff = c8 * 16u;
  float acc[8] = {};
  int j = 0;
  for (; j + 2 <= deg; j += 2) {
    unsigned mA = mp[j];
    unsigned mB = mp[j + 1];
    half8 vA = *(const half8*)(fb + (mA & 0xffffu) * 128u + coff);
    half8 vB = *(const half8*)(fb + (mB & 0xffffu) * 128u + coff);
    float wA = __half2float(__ushort_as_half((unsigned short)(mA >> 16)));
    float wB = __half2float(__ushort_as_half((unsigned short)(mB >> 16)));
#pragma unroll
    for (int c = 0; c < 8; ++c) acc[c] += (float)vA[c] * wA;
#pragma unroll
    for (int c = 0; c < 8; ++c) acc[c] += (float)vB[c] * wB;
  }
  if (j < deg) {
    unsigned mA = mp[j];
    half8 vA = *(const half8*)(fb + (mA & 0xffffu) * 128u + coff);
    float wA = __half2float(__ushort_as_half((unsigned short)(mA >> 16)));
#pragma unroll
    for (int c = 0; c < 8; ++c) acc[c] += (float)vA[c] * wA;
  }
  half8 o;
#pragma unroll
  for (int c = 0; c < 8; ++c) o[c] = (_Float16)acc[c];
  *(half8*)(outp + (size_t)panel * PSTRIDE + (size_t)node * 64 + c8 * 8) = o;
}

// ---- XCD swizzle, exact 784 blocks: 768 = 24 m-groups-of-8 x 4n (u=b&7 -> XCD);
// tail 16 = m-tiles 192..195 x 4n.
__device__ __forceinline__ void gemm_map(int b, int& m0, int& n0) {
  if (b < 768) {
    int u = b & 7;
    int v = b >> 3;
    m0 = ((v >> 2) * 8 + u) * 128;
    n0 = (v & 3) * 128;
  } else {
    int r = b - 768;
    m0 = (192 + (r >> 2)) * 128;
    n0 = (r & 3) * 128;
  }
}

// ---------------- BARRIER-FREE fp16 MFMA GEMM (A panel-major, fragments loaded
// directly from global; no LDS, no __syncthreads -> compiler software-pipelines
// loads across K-iterations with fine-grained vmcnt).
__global__ __launch_bounds__(256, 3)
void gemm_bt_relu(const short* __restrict__ A0, const short* __restrict__ A1,
                  const short* __restrict__ BT, const float* __restrict__ bias,
                  unsigned short* __restrict__ Outp, int M, int S) {
  const int K = 2 * S;
  int m0, n0;
  gemm_map(blockIdx.x, m0, n0);
  const int tid = threadIdx.x;
  const int wave = tid >> 6;
  const int lane = tid & 63;
  const int quad = lane >> 4;
  const int r = lane & 15;
  const int wm = (wave >> 1) * 64;
  const int wn = (wave & 1) * 64;

  // fragment row offsets (in halfs), constant across K
  size_t arow[4], brow[4];
#pragma unroll
  for (int tm = 0; tm < 4; ++tm) {
    int rg = m0 + wm + tm * 16 + r;
    if (rg > M - 1) rg = M - 1;          // clamped rows only affect masked-out outputs
    arow[tm] = (size_t)rg * 64 + quad * 8;
  }
#pragma unroll
  for (int tn = 0; tn < 4; ++tn)
    brow[tn] = (size_t)(n0 + wn + tn * 16 + r) * K + quad * 8;

  f32x4 acc[4][4] = {};

  const int nk = K >> 6;
  for (int kt = 0; kt < nk; ++kt) {
    const int kbase = kt << 6;
    const short* Ab;
    int koff;
    if (kbase < S) { Ab = A0; koff = kbase; } else { Ab = A1; koff = kbase - S; }
    const short* Apan = Ab + (size_t)(koff >> 6) * PSTRIDE;
    half8 af[2][4], bfr[2][4];
#pragma unroll
    for (int ks = 0; ks < 2; ++ks) {
#pragma unroll
      for (int tm = 0; tm < 4; ++tm)
        af[ks][tm] = *(const half8*)(Apan + arow[tm] + ks * 32);
#pragma unroll
      for (int tn = 0; tn < 4; ++tn)
        bfr[ks][tn] = *(const half8*)(BT + brow[tn] + kbase + ks * 32);
    }
#pragma unroll
    for (int ks = 0; ks < 2; ++ks)
#pragma unroll
      for (int tm = 0; tm < 4; ++tm)
#pragma unroll
        for (int tn = 0; tn < 4; ++tn)
          acc[tm][tn] = __builtin_amdgcn_mfma_f32_16x16x32_f16(af[ks][tm], bfr[ks][tn], acc[tm][tn], 0, 0, 0);
  }

#pragma unroll
  for (int tm = 0; tm < 4; ++tm) {
    int rowb = m0 + wm + tm * 16 + quad * 4;
#pragma unroll
    for (int tn = 0; tn < 4; ++tn) {
      int col = n0 + wn + tn * 16 + r;
      float bv = bias[col];
      unsigned short* obase = Outp + (size_t)(col >> 6) * PSTRIDE + (col & 63);
#pragma unroll
      for (int reg = 0; reg < 4; ++reg) {
        int rr = rowb + reg;
        if (rr < M) {
          float v = acc[tm][tn][reg] + bv;
          v = v > 0.f ? v : 0.f;
          obase[(size_t)rr * 64] = f2h(v);
        }
      }
    }
  }
}

// ---------------- BARRIER-FREE GEMM2 + fused mean-pool
__global__ __launch_bounds__(256, 3)
void gemm_bt_pool(const short* __restrict__ A0, const short* __restrict__ A1,
                  const short* __restrict__ BT, const float* __restrict__ bias,
                  const int* __restrict__ batch, float* __restrict__ gsum, int M, int S) {
  const int K = 2 * S;
  int m0, n0;
  gemm_map(blockIdx.x, m0, n0);
  const int tid = threadIdx.x;
  const int wave = tid >> 6;
  const int lane = tid & 63;
  const int quad = lane >> 4;
  const int r = lane & 15;
  const int wm = (wave >> 1) * 64;
  const int wn = (wave & 1) * 64;

  size_t arow[4], brow[4];
#pragma unroll
  for (int tm = 0; tm < 4; ++tm) {
    int rg = m0 + wm + tm * 16 + r;
    if (rg > M - 1) rg = M - 1;
    arow[tm] = (size_t)rg * 64 + quad * 8;
  }
#pragma unroll
  for (int tn = 0; tn < 4; ++tn)
    brow[tn] = (size_t)(n0 + wn + tn * 16 + r) * K + quad * 8;

  f32x4 acc[4][4] = {};

  const int nk = K >> 6;
  for (int kt = 0; kt < nk; ++kt) {
    const int kbase = kt << 6;
    const short* Ab;
    int koff;
    if (kbase < S) { Ab = A0; koff = kbase; } else { Ab = A1; koff = kbase - S; }
    const short* Apan = Ab + (size_t)(koff >> 6) * PSTRIDE;
    half8 af[2][4], bfr[2][4];
#pragma unroll
    for (int ks = 0; ks < 2; ++ks) {
#pragma unroll
      for (int tm = 0; tm < 4; ++tm)
        af[ks][tm] = *(const half8*)(Apan + arow[tm] + ks * 32);
#pragma unroll
      for (int tn = 0; tn < 4; ++tn)
        bfr[ks][tn] = *(const half8*)(BT + brow[tn] + kbase + ks * 32);
    }
#pragma unroll
    for (int ks = 0; ks < 2; ++ks)
#pragma unroll
      for (int tm = 0; tm < 4; ++tm)
#pragma unroll
        for (int tn = 0; tn < 4; ++tn)
          acc[tm][tn] = __builtin_amdgcn_mfma_f32_16x16x32_f16(af[ks][tm], bfr[ks][tn], acc[tm][tn], 0, 0, 0);
  }

  // epilogue: relu(+bias), zero invalid rows, per-graph column sums -> atomicAdd(gsum)
  int gid[4][4];
#pragma unroll
  for (int tm = 0; tm < 4; ++tm) {
    int rowb = m0 + wm + tm * 16 + quad * 4;
#pragma unroll
    for (int reg = 0; reg < 4; ++reg) {
      int rr = rowb + reg;
      gid[tm][reg] = batch[rr < M ? rr : (M - 1)];
    }
#pragma unroll
    for (int tn = 0; tn < 4; ++tn) {
      float bv = bias[n0 + wn + tn * 16 + r];
#pragma unroll
      for (int reg = 0; reg < 4; ++reg) {
        int rr = rowb + reg;
        float v = acc[tm][tn][reg] + bv;
        v = v > 0.f ? v : 0.f;
        acc[tm][tn][reg] = (rr < M) ? v : 0.f;
      }
    }
  }
  int g_lo = batch[m0 < M ? m0 : (M - 1)];
  int g_hi = batch[(m0 + 127) < M ? (m0 + 127) : (M - 1)];
  for (int g = g_lo; g <= g_hi; ++g) {
#pragma unroll
    for (int tn = 0; tn < 4; ++tn) {
      float s = 0.f;
#pragma unroll
      for (int tm = 0; tm < 4; ++tm)
#pragma unroll
        for (int reg = 0; reg < 4; ++reg)
          s += (gid[tm][reg] == g) ? acc[tm][tn][reg] : 0.f;
      s += __shfl_xor(s, 16);
      s += __shfl_xor(s, 32);
      if (quad == 0)
        atomicAdd(&gsum[(size_t)g * HIDC + n0 + wn + tn * 16 + r], s);
    }
  }
}

// ---------------- MLP head (256 threads: 4-way split over the 512-dim input)
__global__ __launch_bounds__(256)
void mlp_kernel(const float* __restrict__ gsum, const int* __restrict__ batch,
                const float* __restrict__ Wl1, const float* __restrict__ bl1,
                const float* __restrict__ Wl2, const float* __restrict__ bl2,
                const float* __restrict__ Wl3, const float* __restrict__ bl3,
                float* __restrict__ out) {
  int gi = blockIdx.x;
  int t = threadIdx.x;
  int unit = t & 63;
  int part = t >> 6;  // 4 parts of 128
  __shared__ float red[4][64];
  __shared__ float h1s[64];
  __shared__ float h2s[16];
  int lo = 0, hi = N_NODESC;
  while (lo < hi) { int mid = (lo + hi) >> 1; if (batch[mid] < gi) lo = mid + 1; else hi = mid; }
  int start = lo;
  hi = N_NODESC;
  while (lo < hi) { int mid = (lo + hi) >> 1; if (batch[mid] < gi + 1) lo = mid + 1; else hi = mid; }
  float inv = 1.0f / fmaxf((float)(lo - start), 1.0f);
  const float* gr = gsum + gi * HIDC;
  float acc = 0.f;
  for (int j = part * 128; j < (part + 1) * 128; ++j)
    acc += gr[j] * Wl1[j * 64 + unit];
  red[part][unit] = acc;
  __syncthreads();
  if (t < 64) {
    float a = bl1[t] + (red[0][t] + red[1][t] + red[2][t] + red[3][t]) * inv;
    h1s[t] = fmaxf(a, 0.f);
  }
  __syncthreads();
  if (t < 16) {
    float a = bl2[t];
    for (int j = 0; j < 64; ++j) a += h1s[j] * Wl2[j * 16 + t];
    h2s[t] = fmaxf(a, 0.f);
  }
  __syncthreads();
  if (t == 0) {
    float a = bl3[0];
    for (int j = 0; j < 16; ++j) a += h2s[j] * Wl3[j];
    out[gi] = a;
  }
}

extern "C" void kernel_launch(void* const* d_in, const int* in_sizes, int n_in,
                              void* d_out, int out_size, void* d_ws, size_t ws_size,
                              hipStream_t stream) {
  const float* x      = (const float*)d_in[0];
  const int*   ei     = (const int*)d_in[1];
  const float* ea     = (const float*)d_in[2];
  const int*   batch  = (const int*)d_in[3];
  const float* W1rel  = (const float*)d_in[4];
  const float* b1     = (const float*)d_in[5];
  const float* W1root = (const float*)d_in[6];
  const float* W2rel  = (const float*)d_in[7];
  const float* b2     = (const float*)d_in[8];
  const float* W2root = (const float*)d_in[9];
  const float* Wl1    = (const float*)d_in[10];
  const float* bl1    = (const float*)d_in[11];
  const float* Wl2    = (const float*)d_in[12];
  const float* bl2    = (const float*)d_in[13];
  const float* Wl3    = (const float*)d_in[14];
  const float* bl3    = (const float*)d_in[15];
  float* out = (float*)d_out;

  // workspace layout (bytes, 16B-aligned). All node features fp16 PANEL-MAJOR [P][25000][64].
  char* ws = (char*)d_ws;
  unsigned short* xp     = (unsigned short*)(ws + 0);           //  6.4 MB (2 panels)
  unsigned short* agg1p  = (unsigned short*)(ws + 6400000);     //  6.4 MB (2 panels)
  unsigned short* h1p    = (unsigned short*)(ws + 12800000);    // 25.6 MB (8 panels)
  unsigned short* agg2p  = (unsigned short*)(ws + 38400000);    // 25.6 MB (8 panels)
  unsigned short* W1T    = (unsigned short*)(ws + 64000000);    // 256 KB
  unsigned short* W2T    = (unsigned short*)(ws + 64262144);    //   1 MB
  float*          gsum   = (float*)(ws + 65310720);             // 128 KB
  int*            deg    = (int*)(ws + 65441792);               // 100 KB + sentinel
  int*            cursor = (int*)(ws + 65541796);               // 100 KB
  int*            indptr = (int*)(ws + 65641796);               // 100 KB+16
  unsigned*       emeta  = (unsigned*)(ws + 65741812);          //  1.6 MB (exact CSR)
  int*            sorted = (int*)(ws + 67341812);               // 100 KB

  // 1) fused prep: deg histogram (uniform-base) + x->fp16 panels + wt + zero gsum
  prep_kernel<<<4976, 256, 0, stream>>>(x, ei, W1rel, W1root, W2rel, W2root,
                                        xp, W1T, W2T, deg, gsum);
  // 2) scan (+ base subtraction, counting sort by degree)
  scan_kernel<<<1, 1024, 0, stream>>>(deg, indptr, cursor, sorted);
  // 3) CSR fill
  fill_kernel<<<(N_EDGESC + 255) / 256, 256, 0, stream>>>(ei, ea, cursor, emeta);

  // 4) layer-1 aggregation: 2 panels (panel = blk&1); 32 nodes/block
  const int NBLK = (N_NODESC + 31) / 32;   // 782
  agg_gather_s<<<NBLK * 2, 256, 0, stream>>>(xp, indptr, emeta, sorted, agg1p, 1);

  // 5) GEMM1 (barrier-free): h1p = relu([agg1|x] @ [W1rel;W1root] + b1)
  gemm_bt_relu<<<784, 256, 0, stream>>>((const short*)agg1p, (const short*)xp,
                                        (const short*)W1T, b1, h1p, N_NODESC, 128);

  // 6) layer-2 aggregation: 8 panels (panel = blk&7 -> per-XCD L2-resident)
  agg_gather_s<<<NBLK * 8, 256, 0, stream>>>(h1p, indptr, emeta, sorted, agg2p, 3);

  // 7) GEMM2 (barrier-free) + fused mean-pool
  gemm_bt_pool<<<784, 256, 0, stream>>>((const short*)agg2p, (const short*)h1p,
                                        (const short*)W2T, b2, batch, gsum, N_NODESC, 512);

  // 8) MLP head (divides by counts)
  mlp_kernel<<<N_GRAPHSC, 256, 0, stream>>>(gsum, batch, Wl1, bl1, Wl2, bl2, Wl3, bl3, out);
}

// Round 16
// 296.107 us; speedup vs baseline: 1.3193x; 1.3193x over previous
//
#include <hip/hip_runtime.h>
#include <hip/hip_bf16.h>
#include <hip/hip_fp16.h>
#include <stdint.h>

#define N_NODESC 25000
#define N_EDGESC 400000
#define N_GRAPHSC 64
#define F_INC 128
#define HIDC 512
#define PSTRIDE 1600000   // elements per 64-col panel: 25000*64
#define MTILES 196        // ceil(25000/128)

typedef __attribute__((ext_vector_type(8))) short short8;
typedef __attribute__((ext_vector_type(8))) _Float16 half8;
typedef __attribute__((ext_vector_type(4))) float f32x4;

__device__ __forceinline__ unsigned short f2h(float f) {
  return __half_as_ushort(__float2half_rn(f));
}

// ================= fused prep (1 launch):
//  blocks [0,1563): degree count via atomicAdd on UNIFORM-init deg (poison-agnostic;
//                   true degree recovered in scan via sentinel deg[25000])
//  blocks [1563,4688): x -> fp16 panel-major
//  blocks [4688,4848): weight transposes (LDS tiles)
//  blocks [4848,4976): zero gsum
__global__ __launch_bounds__(256)
void prep_kernel(const float* __restrict__ x, const int* __restrict__ ei,
                 const float* __restrict__ W1rel, const float* __restrict__ W1root,
                 const float* __restrict__ W2rel, const float* __restrict__ W2root,
                 unsigned short* __restrict__ xp, unsigned short* __restrict__ W1T,
                 unsigned short* __restrict__ W2T, int* __restrict__ deg,
                 float* __restrict__ gsum) {
  int blk = blockIdx.x, t = threadIdx.x;
  if (blk < 1563) {                              // degree histogram (no pre-zero needed)
    int e = blk * 256 + t;
    if (e < N_EDGESC) atomicAdd(&deg[ei[N_EDGESC + e]], 1);
  } else if (blk < 4688) {                       // 3125 blocks: 3.2M elems / 4
    int idx = ((blk - 1563) * 256 + t) * 4;
    int node = idx >> 7;
    int col = idx & 127;
    float4 v = *(const float4*)(x + idx);
    ushort4 o;
    o.x = f2h(v.x); o.y = f2h(v.y); o.z = f2h(v.z); o.w = f2h(v.w);
    *(ushort4*)(xp + (size_t)(col >> 6) * PSTRIDE + (size_t)node * 64 + (col & 63)) = o;
  } else if (blk < 4848) {                       // 160 blocks: weight transposes
    __shared__ float tile[64][65];
    int b2 = blk - 4688;
    const float* src;
    unsigned short* dst;
    int n0, k0, Kout;
    if (b2 < 128) {                              // W2: k-tiles 16, n-tiles 8
      int kt = b2 >> 3, nt = b2 & 7;
      k0 = kt * 64; n0 = nt * 64;
      src = (k0 < 512) ? (W2rel + (size_t)k0 * 512) : (W2root + (size_t)(k0 - 512) * 512);
      dst = W2T; Kout = 1024;
    } else {                                     // W1: k-tiles 4, n-tiles 8
      int b = b2 - 128;
      int kt = b >> 3, nt = b & 7;
      k0 = kt * 64; n0 = nt * 64;
      src = (k0 < 128) ? (W1rel + (size_t)k0 * 512) : (W1root + (size_t)(k0 - 128) * 512);
      dst = W1T; Kout = 256;
    }
    int c = t & 63;
    int r4 = t >> 6;
#pragma unroll
    for (int rr = 0; rr < 64; rr += 4) {
      int row = rr + r4;
      tile[c][row] = src[(size_t)row * 512 + n0 + c];
    }
    __syncthreads();
#pragma unroll
    for (int rr = 0; rr < 64; rr += 4) {
      int nrow = rr + r4;
      dst[(size_t)(n0 + nrow) * Kout + k0 + c] = f2h(tile[nrow][c]);
    }
  } else {                                       // 128 blocks: gsum 64x512
    int i = (blk - 4848) * 256 + t;
    if (i < N_GRAPHSC * HIDC) gsum[i] = 0.f;
  }
}

// single-block: subtract uniform base (sentinel deg[N_NODESC] untouched by prep),
// exclusive scan -> indptr/cursor, counting sort of node ids by degree -> sorted.
__global__ __launch_bounds__(1024)
void scan_kernel(const int* __restrict__ deg, int* __restrict__ indptr, int* __restrict__ cursor,
                 int* __restrict__ sorted) {
  __shared__ int sums[1024];
  __shared__ int bins[256];
  __shared__ int binptr[256];
  const int t = threadIdx.x;
  const int CH = (N_NODESC + 1023) / 1024;  // 25
  const int base = t * CH;
  const unsigned ub = (unsigned)deg[N_NODESC];   // uniform init value (poison or 0)
  if (t < 256) bins[t] = 0;
  __syncthreads();
  int dl[CH];
  int s = 0;
  for (int i = 0; i < CH; ++i) {
    int idx = base + i;
    int d = (idx < N_NODESC) ? (int)((unsigned)deg[idx] - ub) : -1;
    dl[i] = d;
    if (d >= 0) {
      s += d;
      atomicAdd(&bins[d > 255 ? 255 : d], 1);
    }
  }
  sums[t] = s;
  __syncthreads();
  for (int off = 1; off < 1024; off <<= 1) {
    int v = (t >= off) ? sums[t - off] : 0;
    __syncthreads();
    sums[t] += v;
    __syncthreads();
  }
  if (t == 0) {
    int run = 0;
    for (int b = 0; b < 256; ++b) { binptr[b] = run; run += bins[b]; }
  }
  __syncthreads();
  int run = (t > 0) ? sums[t - 1] : 0;
  for (int i = 0; i < CH; ++i) {
    int idx = base + i;
    if (idx < N_NODESC) {
      indptr[idx] = run;
      cursor[idx] = run;
      run += dl[i];
      int pos = atomicAdd(&binptr[dl[i] > 255 ? 255 : dl[i]], 1);
      sorted[pos] = idx;
    }
  }
  if (t == 0) indptr[N_NODESC] = sums[1023];
}

// packed edge meta: src (16b) | fp16 weight (16b)
__global__ void fill_kernel(const int* __restrict__ ei, const float* __restrict__ ea,
                            int* __restrict__ cursor, unsigned* __restrict__ emeta) {
  int e = blockIdx.x * blockDim.x + threadIdx.x;
  if (e >= N_EDGESC) return;
  int dst = ei[N_EDGESC + e];
  int pos = atomicAdd(&cursor[dst], 1);
  unsigned short hw = __half_as_ushort(__float2half_rn(ea[e]));
  emeta[pos] = (unsigned)ei[e] | ((unsigned)hw << 16);
}

// ================= panel-major CSR gather (L2-blocked, 8 nodes per wave, fp16) =====
__global__ __launch_bounds__(256)
void agg_gather_s(const unsigned short* __restrict__ feat, const int* __restrict__ indptr,
                  const unsigned* __restrict__ emeta, const int* __restrict__ sorted,
                  unsigned short* __restrict__ outp, int lgP) {
  int panel = blockIdx.x & ((1 << lgP) - 1);
  int nidx = (blockIdx.x >> lgP) * 32 + (threadIdx.x >> 3);   // 32 node-slots / block
  if (nidx >= N_NODESC) return;
  int c8 = threadIdx.x & 7;
  int node = sorted[nidx];
  int beg = indptr[node];
  int deg = indptr[node + 1] - beg;
  const unsigned* mp = emeta + beg;
  const char* fb = (const char*)(feat + (size_t)panel * PSTRIDE);
  unsigned coff = c8 * 16u;
  float acc[8] = {};
  int j = 0;
  for (; j + 2 <= deg; j += 2) {
    unsigned mA = mp[j];
    unsigned mB = mp[j + 1];
    half8 vA = *(const half8*)(fb + (mA & 0xffffu) * 128u + coff);
    half8 vB = *(const half8*)(fb + (mB & 0xffffu) * 128u + coff);
    float wA = __half2float(__ushort_as_half((unsigned short)(mA >> 16)));
    float wB = __half2float(__ushort_as_half((unsigned short)(mB >> 16)));
#pragma unroll
    for (int c = 0; c < 8; ++c) acc[c] += (float)vA[c] * wA;
#pragma unroll
    for (int c = 0; c < 8; ++c) acc[c] += (float)vB[c] * wB;
  }
  if (j < deg) {
    unsigned mA = mp[j];
    half8 vA = *(const half8*)(fb + (mA & 0xffffu) * 128u + coff);
    float wA = __half2float(__ushort_as_half((unsigned short)(mA >> 16)));
#pragma unroll
    for (int c = 0; c < 8; ++c) acc[c] += (float)vA[c] * wA;
  }
  half8 o;
#pragma unroll
  for (int c = 0; c < 8; ++c) o[c] = (_Float16)acc[c];
  *(half8*)(outp + (size_t)panel * PSTRIDE + (size_t)node * 64 + c8 * 8) = o;
}

// ---- XCD swizzle, exact 784 blocks: 768 = 24 m-groups-of-8 x 4n (u=b&7 -> XCD);
// tail 16 = m-tiles 192..195 x 4n.
__device__ __forceinline__ void gemm_map(int b, int& m0, int& n0) {
  if (b < 768) {
    int u = b & 7;
    int v = b >> 3;
    m0 = ((v >> 2) * 8 + u) * 128;
    n0 = (v & 3) * 128;
  } else {
    int r = b - 768;
    m0 = (192 + (r >> 2)) * 128;
    n0 = (r & 3) * 128;
  }
}

// ---------------- fp16 MFMA GEMM (A operands PANEL-MAJOR): h1p = relu([A0|A1]@BT^T + b)
__global__ __launch_bounds__(256, 3)
void gemm_bt_relu(const short* __restrict__ A0, const short* __restrict__ A1,
                  const short* __restrict__ BT, const float* __restrict__ bias,
                  unsigned short* __restrict__ Outp, int M, int S) {
  const int K = 2 * S;
  __shared__ __align__(16) short As[128 * 64];
  __shared__ __align__(16) short Bs[128 * 64];
  int m0, n0;
  gemm_map(blockIdx.x, m0, n0);
  const int tid = threadIdx.x;
  const int wave = tid >> 6;
  const int lane = tid & 63;
  const int quad = lane >> 4;
  const int r = lane & 15;
  const int wm = (wave >> 1) * 64;
  const int wn = (wave & 1) * 64;

  f32x4 acc[4][4] = {};

  const int nk = K >> 6;
  for (int kt = 0; kt < nk; ++kt) {
    const int kbase = kt << 6;
    const short* Ab;
    int koff;
    if (kbase < S) { Ab = A0; koff = kbase; } else { Ab = A1; koff = kbase - S; }
    const short* Apan = Ab + (size_t)(koff >> 6) * PSTRIDE;
#pragma unroll
    for (int i = 0; i < 4; ++i) {
      int s = ((wave * 4 + i) << 6) + lane;
      int row = s >> 3;
      int c = (s & 7) ^ (row & 7);
      int rg = m0 + row; if (rg > M - 1) rg = M - 1;
      const short* gp = Apan + (size_t)rg * 64 + (c << 3);
      __builtin_amdgcn_global_load_lds((const __attribute__((address_space(1))) void*)gp,
                                       (__attribute__((address_space(3))) void*)&As[(wave * 4 + i) * 512],
                                       16, 0, 0);
    }
#pragma unroll
    for (int i = 0; i < 4; ++i) {
      int s = ((wave * 4 + i) << 6) + lane;
      int row = s >> 3;
      int c = (s & 7) ^ (row & 7);
      const short* gp = BT + (size_t)(n0 + row) * K + kbase + (c << 3);
      __builtin_amdgcn_global_load_lds((const __attribute__((address_space(1))) void*)gp,
                                       (__attribute__((address_space(3))) void*)&Bs[(wave * 4 + i) * 512],
                                       16, 0, 0);
    }
    __syncthreads();
#pragma unroll
    for (int ks = 0; ks < 2; ++ks) {
      half8 af[4], bfr[4];
#pragma unroll
      for (int tm = 0; tm < 4; ++tm) {
        int ml = wm + tm * 16 + r;
        int c = (ks << 2) + quad;
        int slot = ml * 8 + (c ^ (ml & 7));
        af[tm] = *(const half8*)&As[slot * 8];
      }
#pragma unroll
      for (int tn = 0; tn < 4; ++tn) {
        int nl = wn + tn * 16 + r;
        int c = (ks << 2) + quad;
        int slot = nl * 8 + (c ^ (nl & 7));
        bfr[tn] = *(const half8*)&Bs[slot * 8];
      }
#pragma unroll
      for (int tm = 0; tm < 4; ++tm)
#pragma unroll
        for (int tn = 0; tn < 4; ++tn)
          acc[tm][tn] = __builtin_amdgcn_mfma_f32_16x16x32_f16(af[tm], bfr[tn], acc[tm][tn], 0, 0, 0);
    }
    __syncthreads();
  }

#pragma unroll
  for (int tm = 0; tm < 4; ++tm) {
    int rowb = m0 + wm + tm * 16 + quad * 4;
#pragma unroll
    for (int tn = 0; tn < 4; ++tn) {
      int col = n0 + wn + tn * 16 + r;
      float bv = bias[col];
      unsigned short* obase = Outp + (size_t)(col >> 6) * PSTRIDE + (col & 63);
#pragma unroll
      for (int reg = 0; reg < 4; ++reg) {
        int rr = rowb + reg;
        if (rr < M) {
          float v = acc[tm][tn][reg] + bv;
          v = v > 0.f ? v : 0.f;
          obase[(size_t)rr * 64] = f2h(v);
        }
      }
    }
  }
}

// ---------------- GEMM2 + fused mean-pool (A panel-major): gsum += per-graph col sums
__global__ __launch_bounds__(256, 3)
void gemm_bt_pool(const short* __restrict__ A0, const short* __restrict__ A1,
                  const short* __restrict__ BT, const float* __restrict__ bias,
                  const int* __restrict__ batch, float* __restrict__ gsum, int M, int S) {
  const int K = 2 * S;
  __shared__ __align__(16) short As[128 * 64];
  __shared__ __align__(16) short Bs[128 * 64];
  int m0, n0;
  gemm_map(blockIdx.x, m0, n0);
  const int tid = threadIdx.x;
  const int wave = tid >> 6;
  const int lane = tid & 63;
  const int quad = lane >> 4;
  const int r = lane & 15;
  const int wm = (wave >> 1) * 64;
  const int wn = (wave & 1) * 64;

  f32x4 acc[4][4] = {};

  const int nk = K >> 6;
  for (int kt = 0; kt < nk; ++kt) {
    const int kbase = kt << 6;
    const short* Ab;
    int koff;
    if (kbase < S) { Ab = A0; koff = kbase; } else { Ab = A1; koff = kbase - S; }
    const short* Apan = Ab + (size_t)(koff >> 6) * PSTRIDE;
#pragma unroll
    for (int i = 0; i < 4; ++i) {
      int s = ((wave * 4 + i) << 6) + lane;
      int row = s >> 3;
      int c = (s & 7) ^ (row & 7);
      int rg = m0 + row; if (rg > M - 1) rg = M - 1;
      const short* gp = Apan + (size_t)rg * 64 + (c << 3);
      __builtin_amdgcn_global_load_lds((const __attribute__((address_space(1))) void*)gp,
                                       (__attribute__((address_space(3))) void*)&As[(wave * 4 + i) * 512],
                                       16, 0, 0);
    }
#pragma unroll
    for (int i = 0; i < 4; ++i) {
      int s = ((wave * 4 + i) << 6) + lane;
      int row = s >> 3;
      int c = (s & 7) ^ (row & 7);
      const short* gp = BT + (size_t)(n0 + row) * K + kbase + (c << 3);
      __builtin_amdgcn_global_load_lds((const __attribute__((address_space(1))) void*)gp,
                                       (__attribute__((address_space(3))) void*)&Bs[(wave * 4 + i) * 512],
                                       16, 0, 0);
    }
    __syncthreads();
#pragma unroll
    for (int ks = 0; ks < 2; ++ks) {
      half8 af[4], bfr[4];
#pragma unroll
      for (int tm = 0; tm < 4; ++tm) {
        int ml = wm + tm * 16 + r;
        int c = (ks << 2) + quad;
        int slot = ml * 8 + (c ^ (ml & 7));
        af[tm] = *(const half8*)&As[slot * 8];
      }
#pragma unroll
      for (int tn = 0; tn < 4; ++tn) {
        int nl = wn + tn * 16 + r;
        int c = (ks << 2) + quad;
        int slot = nl * 8 + (c ^ (nl & 7));
        bfr[tn] = *(const half8*)&Bs[slot * 8];
      }
#pragma unroll
      for (int tm = 0; tm < 4; ++tm)
#pragma unroll
        for (int tn = 0; tn < 4; ++tn)
          acc[tm][tn] = __builtin_amdgcn_mfma_f32_16x16x32_f16(af[tm], bfr[tn], acc[tm][tn], 0, 0, 0);
    }
    __syncthreads();
  }

  // epilogue: relu(+bias), zero invalid rows, per-graph column sums -> atomicAdd(gsum)
  int gid[4][4];
#pragma unroll
  for (int tm = 0; tm < 4; ++tm) {
    int rowb = m0 + wm + tm * 16 + quad * 4;
#pragma unroll
    for (int reg = 0; reg < 4; ++reg) {
      int rr = rowb + reg;
      gid[tm][reg] = batch[rr < M ? rr : (M - 1)];
    }
#pragma unroll
    for (int tn = 0; tn < 4; ++tn) {
      float bv = bias[n0 + wn + tn * 16 + r];
#pragma unroll
      for (int reg = 0; reg < 4; ++reg) {
        int rr = rowb + reg;
        float v = acc[tm][tn][reg] + bv;
        v = v > 0.f ? v : 0.f;
        acc[tm][tn][reg] = (rr < M) ? v : 0.f;
      }
    }
  }
  int g_lo = batch[m0 < M ? m0 : (M - 1)];
  int g_hi = batch[(m0 + 127) < M ? (m0 + 127) : (M - 1)];
  for (int g = g_lo; g <= g_hi; ++g) {
#pragma unroll
    for (int tn = 0; tn < 4; ++tn) {
      float s = 0.f;
#pragma unroll
      for (int tm = 0; tm < 4; ++tm)
#pragma unroll
        for (int reg = 0; reg < 4; ++reg)
          s += (gid[tm][reg] == g) ? acc[tm][tn][reg] : 0.f;
      s += __shfl_xor(s, 16);
      s += __shfl_xor(s, 32);
      if (quad == 0)
        atomicAdd(&gsum[(size_t)g * HIDC + n0 + wn + tn * 16 + r], s);
    }
  }
}

// ---------------- MLP head (256 threads: 4-way split over the 512-dim input)
__global__ __launch_bounds__(256)
void mlp_kernel(const float* __restrict__ gsum, const int* __restrict__ batch,
                const float* __restrict__ Wl1, const float* __restrict__ bl1,
                const float* __restrict__ Wl2, const float* __restrict__ bl2,
                const float* __restrict__ Wl3, const float* __restrict__ bl3,
                float* __restrict__ out) {
  int gi = blockIdx.x;
  int t = threadIdx.x;
  int unit = t & 63;
  int part = t >> 6;  // 4 parts of 128
  __shared__ float red[4][64];
  __shared__ float h1s[64];
  __shared__ float h2s[16];
  int lo = 0, hi = N_NODESC;
  while (lo < hi) { int mid = (lo + hi) >> 1; if (batch[mid] < gi) lo = mid + 1; else hi = mid; }
  int start = lo;
  hi = N_NODESC;
  while (lo < hi) { int mid = (lo + hi) >> 1; if (batch[mid] < gi + 1) lo = mid + 1; else hi = mid; }
  float inv = 1.0f / fmaxf((float)(lo - start), 1.0f);
  const float* gr = gsum + gi * HIDC;
  float acc = 0.f;
  for (int j = part * 128; j < (part + 1) * 128; ++j)
    acc += gr[j] * Wl1[j * 64 + unit];
  red[part][unit] = acc;
  __syncthreads();
  if (t < 64) {
    float a = bl1[t] + (red[0][t] + red[1][t] + red[2][t] + red[3][t]) * inv;
    h1s[t] = fmaxf(a, 0.f);
  }
  __syncthreads();
  if (t < 16) {
    float a = bl2[t];
    for (int j = 0; j < 64; ++j) a += h1s[j] * Wl2[j * 16 + t];
    h2s[t] = fmaxf(a, 0.f);
  }
  __syncthreads();
  if (t == 0) {
    float a = bl3[0];
    for (int j = 0; j < 16; ++j) a += h2s[j] * Wl3[j];
    out[gi] = a;
  }
}

extern "C" void kernel_launch(void* const* d_in, const int* in_sizes, int n_in,
                              void* d_out, int out_size, void* d_ws, size_t ws_size,
                              hipStream_t stream) {
  const float* x      = (const float*)d_in[0];
  const int*   ei     = (const int*)d_in[1];
  const float* ea     = (const float*)d_in[2];
  const int*   batch  = (const int*)d_in[3];
  const float* W1rel  = (const float*)d_in[4];
  const float* b1     = (const float*)d_in[5];
  const float* W1root = (const float*)d_in[6];
  const float* W2rel  = (const float*)d_in[7];
  const float* b2     = (const float*)d_in[8];
  const float* W2root = (const float*)d_in[9];
  const float* Wl1    = (const float*)d_in[10];
  const float* bl1    = (const float*)d_in[11];
  const float* Wl2    = (const float*)d_in[12];
  const float* bl2    = (const float*)d_in[13];
  const float* Wl3    = (const float*)d_in[14];
  const float* bl3    = (const float*)d_in[15];
  float* out = (float*)d_out;

  // workspace layout (bytes, 16B-aligned). All node features fp16 PANEL-MAJOR [P][25000][64].
  char* ws = (char*)d_ws;
  unsigned short* xp     = (unsigned short*)(ws + 0);           //  6.4 MB (2 panels)
  unsigned short* agg1p  = (unsigned short*)(ws + 6400000);     //  6.4 MB (2 panels)
  unsigned short* h1p    = (unsigned short*)(ws + 12800000);    // 25.6 MB (8 panels)
  unsigned short* agg2p  = (unsigned short*)(ws + 38400000);    // 25.6 MB (8 panels)
  unsigned short* W1T    = (unsigned short*)(ws + 64000000);    // 256 KB
  unsigned short* W2T    = (unsigned short*)(ws + 64262144);    //   1 MB
  float*          gsum   = (float*)(ws + 65310720);             // 128 KB
  int*            deg    = (int*)(ws + 65441792);               // 100 KB + sentinel
  int*            cursor = (int*)(ws + 65541796);               // 100 KB
  int*            indptr = (int*)(ws + 65641796);               // 100 KB+16
  unsigned*       emeta  = (unsigned*)(ws + 65741812);          //  1.6 MB (exact CSR)
  int*            sorted = (int*)(ws + 67341812);               // 100 KB

  // 1) fused prep: deg histogram (uniform-base) + x->fp16 panels + wt + zero gsum
  prep_kernel<<<4976, 256, 0, stream>>>(x, ei, W1rel, W1root, W2rel, W2root,
                                        xp, W1T, W2T, deg, gsum);
  // 2) scan (+ base subtraction, counting sort by degree)
  scan_kernel<<<1, 1024, 0, stream>>>(deg, indptr, cursor, sorted);
  // 3) CSR fill
  fill_kernel<<<(N_EDGESC + 255) / 256, 256, 0, stream>>>(ei, ea, cursor, emeta);

  // 4) layer-1 aggregation: 2 panels (panel = blk&1); 32 nodes/block
  const int NBLK = (N_NODESC + 31) / 32;   // 782
  agg_gather_s<<<NBLK * 2, 256, 0, stream>>>(xp, indptr, emeta, sorted, agg1p, 1);

  // 5) GEMM1: h1p = relu([agg1|x] @ [W1rel;W1root] + b1)   (M=25000, K=256, N=512)
  gemm_bt_relu<<<784, 256, 0, stream>>>((const short*)agg1p, (const short*)xp,
                                        (const short*)W1T, b1, h1p, N_NODESC, 128);

  // 6) layer-2 aggregation: 8 panels (panel = blk&7 -> per-XCD L2-resident)
  agg_gather_s<<<NBLK * 8, 256, 0, stream>>>(h1p, indptr, emeta, sorted, agg2p, 3);

  // 7) GEMM2 + fused mean-pool
  gemm_bt_pool<<<784, 256, 0, stream>>>((const short*)agg2p, (const short*)h1p,
                                        (const short*)W2T, b2, batch, gsum, N_NODESC, 512);

  // 8) MLP head (divides by counts)
  mlp_kernel<<<N_GRAPHSC, 256, 0, stream>>>(gsum, batch, Wl1, bl1, Wl2, bl2, Wl3, bl3, out);
}